// Round 15
// baseline (81.925 us; speedup 1.0000x reference)
//
#include <hip/hip_runtime.h>
#include <hip/hip_fp16.h>
#include <cstdint>
#include <cstddef>

#define HH 240
#define WW 320
#define HWPIX 76800
#define NVIEW 4
#define NCH 32
#define NGRP 8
#define NDEP 8
#define NNEI 9
#define QPLANE (HWPIX * 8)     // halfs per quarter-plane (8 ch/pixel)

// ws layout (floats):
// [0..48)   proj: 4 views * 12 (rot 9 row-major, trans 3)
// [62],[63] b2 for pw / sn
// [64..)    per-lane MFMA fragment tables, per net (stride 1024 floats)
#define OFF_TAB 64
#define OFF_Y    4096                     // NDEP*HWPIX f32, layout [pix][d]
#define OFF_SRCT 618496                   // as __half*: 20 quarter-planes (16 src + 4 ref)

typedef _Float16 h2 __attribute__((ext_vector_type(2)));
typedef __fp16  h8v __attribute__((ext_vector_type(8)));
typedef float f32x16 __attribute__((ext_vector_type(16)));

__device__ __forceinline__ float fdot2_(h2 a, h2 b, float c) {
#if __has_builtin(__builtin_amdgcn_fdot2)
  return __builtin_amdgcn_fdot2(a, b, c, false);
#else
  return c + (float)a.x * (float)b.x + (float)a.y * (float)b.y;
#endif
}
__device__ __forceinline__ h2 pk_(float a, float b) {
#if __has_builtin(__builtin_amdgcn_cvt_pkrtz)
  return __builtin_bit_cast(h2, __builtin_amdgcn_cvt_pkrtz(a, b));
#else
  h2 r; r.x = (_Float16)a; r.y = (_Float16)b; return r;
#endif
}
__device__ __forceinline__ float pkf_(float a, float b) {
  return __builtin_bit_cast(float, pk_(a, b));
}

__device__ __forceinline__ f32x16 mfma_(h8v a, h8v b, f32x16 c) {
  return __builtin_amdgcn_mfma_f32_32x32x16_f16(a, b, c, 0, 0, 0);
}

// Wave-batched MLP 8->16->8->1 via 32x32x16 f16 MFMA (layer0 bias in K-slots 8..15)
__device__ __forceinline__ float mlp_mfma(float4 x4, h8v w0f, h8v w1f,
                                          float4 b1s, float4 w2s, float b2v,
                                          bool lo) {
  f32x16 Z = {};
  float4 xsw;
  xsw.x = __shfl_xor(x4.x, 32, 64);
  xsw.y = __shfl_xor(x4.y, 32, 64);
  xsw.z = __shfl_xor(x4.z, 32, 64);
  xsw.w = __shfl_xor(x4.w, 32, 64);
  float4 cst;
  cst.x = __builtin_bit_cast(float, 0x00003C00u);   // h2(1.0, 0) -> bias K-slot
  cst.y = 0.0f; cst.z = 0.0f; cst.w = 0.0f;
  float4 blo, bhi;
  blo.x = lo ? x4.x : cst.x;  blo.y = lo ? x4.y : cst.y;
  blo.z = lo ? x4.z : cst.z;  blo.w = lo ? x4.w : cst.w;
  bhi.x = lo ? xsw.x : cst.x; bhi.y = lo ? xsw.y : cst.y;
  bhi.z = lo ? xsw.z : cst.z; bhi.w = lo ? xsw.w : cst.w;

  float yv0 = 0.0f, yv1 = 0.0f;
#pragma unroll
  for (int bb = 0; bb < 2; ++bb) {
    float4 bin = bb ? bhi : blo;
    f32x16 acc = mfma_(w0f, __builtin_bit_cast(h8v, bin), Z);
    float dw0 = pkf_(fmaxf(acc[0], 0.f), fmaxf(acc[1], 0.f));
    float dw1 = pkf_(fmaxf(acc[2], 0.f), fmaxf(acc[3], 0.f));
    float dw2 = pkf_(fmaxf(acc[4], 0.f), fmaxf(acc[5], 0.f));
    float dw3 = pkf_(fmaxf(acc[6], 0.f), fmaxf(acc[7], 0.f));
    float s0 = __shfl_xor(dw0, 32, 64);
    float s1 = __shfl_xor(dw1, 32, 64);
    float s2 = __shfl_xor(dw2, 32, 64);
    float s3 = __shfl_xor(dw3, 32, 64);
    float4 bf;
    bf.x = lo ? dw0 : s2;
    bf.y = lo ? dw1 : s3;
    bf.z = lo ? s0 : dw2;
    bf.w = lo ? s1 : dw3;
    f32x16 a2 = mfma_(w1f, __builtin_bit_cast(h8v, bf), Z);
    float p = fmaxf(a2[0] + b1s.x, 0.f) * w2s.x;
    p = fmaf(fmaxf(a2[1] + b1s.y, 0.f), w2s.y, p);
    p = fmaf(fmaxf(a2[2] + b1s.z, 0.f), w2s.z, p);
    p = fmaf(fmaxf(a2[3] + b1s.w, 0.f), w2s.w, p);
    p += __shfl_xor(p, 32, 64);
    if (bb) yv1 = p + b2v; else yv0 = p + b2v;
  }
  return lo ? yv0 : yv1;
}

// -------- prep: transpose+convert features into quarter-planes; last block = setup
__global__ __launch_bounds__(256) void k_prep(
    const float* __restrict__ src, const float* __restrict__ ref,
    __half* __restrict__ dst,
    const float* __restrict__ refP, const float* __restrict__ srcP,
    const float* __restrict__ pw0, const float* __restrict__ pbn0,
    const float* __restrict__ pw1, const float* __restrict__ pbn1,
    const float* __restrict__ pw2, const float* __restrict__ pb2,
    const float* __restrict__ sw0, const float* __restrict__ sbn0,
    const float* __restrict__ sw1, const float* __restrict__ sbn1,
    const float* __restrict__ sw2, const float* __restrict__ sb2,
    float* __restrict__ ws, int nTransBlocks) {
  if ((int)blockIdx.x == nTransBlocks) {
    int tid = threadIdx.x;
    if (tid < 128) {
      int net = tid >> 6;
      int l = tid & 63;
      int n = l & 31;
      int hi = l >> 5;
      const float* W0 = net ? sw0 : pw0;  const float* B0 = net ? sbn0 : pbn0;
      const float* W1 = net ? sw1 : pw1;  const float* B1 = net ? sbn1 : pbn1;
      const float* W2 = net ? sw2 : pw2;
      float* base = ws + OFF_TAB + net * 1024;
      float4 r;
      if (hi == 0 && n < 16) {
        float s = B0[n] / sqrtf(B0[48 + n] + 1e-5f) * 0.25f;
        r.x = pkf_(W0[n * 8 + 0] * s, W0[n * 8 + 1] * s);
        r.y = pkf_(W0[n * 8 + 2] * s, W0[n * 8 + 3] * s);
        r.z = pkf_(W0[n * 8 + 4] * s, W0[n * 8 + 5] * s);
        r.w = pkf_(W0[n * 8 + 6] * s, W0[n * 8 + 7] * s);
      } else if (hi == 1 && n < 16) {
        float s = B0[n] / sqrtf(B0[48 + n] + 1e-5f);
        float b0f = B0[16 + n] - B0[32 + n] * s;
        r.x = pkf_(b0f, 0.f); r.y = 0.f; r.z = 0.f; r.w = 0.f;
      } else { r.x = r.y = r.z = r.w = 0.f; }
      ((float4*)(base))[l] = r;
      float4 q;
      if (n < 8) {
        float s = B1[n] / sqrtf(B1[24 + n] + 1e-5f);
        int o = n * 16 + 8 * hi;
        q.x = pkf_(W1[o + 0] * s, W1[o + 1] * s);
        q.y = pkf_(W1[o + 2] * s, W1[o + 3] * s);
        q.z = pkf_(W1[o + 4] * s, W1[o + 5] * s);
        q.w = pkf_(W1[o + 6] * s, W1[o + 7] * s);
      } else { q.x = q.y = q.z = q.w = 0.f; }
      ((float4*)(base + 256))[l] = q;
      float4 b;
      {
        float bb[4];
        for (int rr = 0; rr < 4; ++rr) {
          int o = rr + 4 * hi;
          float s = B1[o] / sqrtf(B1[24 + o] + 1e-5f);
          bb[rr] = B1[8 + o] - B1[16 + o] * s;
        }
        b.x = bb[0]; b.y = bb[1]; b.z = bb[2]; b.w = bb[3];
      }
      ((float4*)(base + 512))[l] = b;
      float4 w2v;
      w2v.x = W2[0 + 4 * hi]; w2v.y = W2[1 + 4 * hi];
      w2v.z = W2[2 + 4 * hi]; w2v.w = W2[3 + 4 * hi];
      ((float4*)(base + 768))[l] = w2v;
    } else if (tid == 128) {
      ws[62] = pb2[0];
      ws[63] = sb2[0];
    } else if (tid == 129) {
      float a[4][8];
      for (int i = 0; i < 4; ++i)
        for (int j = 0; j < 4; ++j) { a[i][j] = refP[i * 4 + j]; a[i][4 + j] = (i == j) ? 1.0f : 0.0f; }
      for (int c = 0; c < 4; ++c) {
        int piv = c; float best = fabsf(a[c][c]);
        for (int r2 = c + 1; r2 < 4; ++r2) { float t = fabsf(a[r2][c]); if (t > best) { best = t; piv = r2; } }
        if (piv != c) for (int j = 0; j < 8; ++j) { float t = a[c][j]; a[c][j] = a[piv][j]; a[piv][j] = t; }
        float inv = 1.0f / a[c][c];
        for (int j = 0; j < 8; ++j) a[c][j] *= inv;
        for (int r2 = 0; r2 < 4; ++r2) if (r2 != c) {
          float f = a[r2][c];
          for (int j = 0; j < 8; ++j) a[r2][j] -= f * a[c][j];
        }
      }
      for (int v = 0; v < NVIEW; ++v) {
        const float* S = srcP + v * 16;
        for (int i = 0; i < 3; ++i)
          for (int j = 0; j < 4; ++j) {
            float p = S[i*4+0]*a[0][4+j] + S[i*4+1]*a[1][4+j] + S[i*4+2]*a[2][4+j] + S[i*4+3]*a[3][4+j];
            if (j < 3) ws[v * 12 + i * 3 + j] = p;
            else       ws[v * 12 + 9 + i] = p;
          }
      }
    }
    return;
  }
  int t = blockIdx.x * 256 + threadIdx.x;
  int vq = t / HWPIX;                    // quarter-plane index 0..19 ((v*4+q); v==4 -> ref)
  int pix = t - vq * HWPIX;
  int v = vq >> 2;
  int q = vq & 3;
  const float* s = (v < NVIEW) ? (src + ((size_t)(v * NCH + q * 8)) * HWPIX + pix)
                               : (ref + ((size_t)(q * 8)) * HWPIX + pix);
  union { h2 h[4]; float4 f; } u;
  u.h[0] = pk_(s[0],         s[HWPIX]);
  u.h[1] = pk_(s[2 * HWPIX], s[3 * HWPIX]);
  u.h[2] = pk_(s[4 * HWPIX], s[5 * HWPIX]);
  u.h[3] = pk_(s[6 * HWPIX], s[7 * HWPIX]);
  reinterpret_cast<float4*>(dst + (size_t)vq * QPLANE)[pix] = u.f;
}

// blend a raw 16B tap (4 h2) into wp with weight wtf
__device__ __forceinline__ void blend4(float4 uf, float wtf, h2* __restrict__ wp) {
  _Float16 wh = (_Float16)wtf;
  h2 wt2 = h2{wh, wh};
  union { float4 f; h2 h[4]; } u; u.f = uf;
#pragma unroll
  for (int c = 0; c < 4; ++c) wp[c] += u.h[c] * wt2;
}

// -------- main fused kernel. Block = 512 threads = 8 waves: wave d handles
// 64 CONSECUTIVE pixels at depth index d (coalesced taps). Phase 1 computes
// all 4 views' sims + pw-scores with NO barriers; one barrier + LDS reduce
// does max-over-d for all views; phase 3 accumulates.
// Tap skipping (R14) + load/blend decoupling (R15): guarded branches contain
// ONLY loads into independent raw registers (no wp dependency), so all of a
// view's active tap loads issue back-to-back and pay one L2 latency; blends
// follow in VALU-only guarded blocks.
__global__ __launch_bounds__(512, 2) void k_main(
    const __half* __restrict__ srcT, const float* __restrict__ depthS,
    const float* __restrict__ wsc,
    float* __restrict__ ybuf, float* __restrict__ outVW) {
  __shared__ float sred[NVIEW * NDEP * 64];
  int tid = threadIdx.x;
  int lane = tid & 63;
  int d = tid >> 6;                      // wave id = depth index
  bool lo = lane < 32;
  // XCD-aware swizzle: 1200 blocks = 8 XCDs x 150 contiguous; bijective.
  int bid = (int)blockIdx.x;
  int swz = (bid & 7) * 150 + (bid >> 3);
  int pix = swz * 64 + lane;             // 64 consecutive pixels per wave
  int h = pix / WW;                      // uniform per wave (64 | 320)
  int w = pix - h * WW;
  float fx = (float)w, fy = (float)h;

  // pw-net fragments
  h8v w0f_pw = ((const h8v*)(wsc + OFF_TAB))[lane];
  h8v w1f_pw = ((const h8v*)(wsc + OFF_TAB + 256))[lane];
  float4 b1s_pw = ((const float4*)(wsc + OFF_TAB + 512))[lane];
  float4 w2s_pw = ((const float4*)(wsc + OFF_TAB + 768))[lane];
  float b2_pw = wsc[62];

  // ref channels: 4 quarter-plane loads, fully coalesced
  h2 rc[16];
  {
    const __half* refb = srcT + (size_t)16 * QPLANE;
#pragma unroll
    for (int q = 0; q < 4; ++q) {
      union { float4 f; h2 hh[4]; } u;
      u.f = *reinterpret_cast<const float4*>(refb + (size_t)q * QPLANE + (size_t)pix * 8);
      rc[4*q] = u.hh[0]; rc[4*q+1] = u.hh[1]; rc[4*q+2] = u.hh[2]; rc[4*q+3] = u.hh[3];
    }
  }
  float dep = depthS[d * HWPIX + pix];   // coalesced (same d across wave)

  // ---- phase 1: all views, no barriers (fully unrolled: arrays stay in regs)
  float4 xps[NVIEW];
  float scv[NVIEW];
#pragma unroll
  for (int v = 0; v < NVIEW; ++v) {
    const float* pr = wsc + v * 12;
    float rx = fmaf(pr[0], fx, fmaf(pr[1], fy, pr[2]));
    float ry = fmaf(pr[3], fx, fmaf(pr[4], fy, pr[5]));
    float rz = fmaf(pr[6], fx, fmaf(pr[7], fy, pr[8]));
    float pz_ = fmaf(rz, dep, pr[11]);
    bool neg = (pz_ <= 0.001f);
    float px_ = neg ? (float)WW : fmaf(rx, dep, pr[9]);
    float py_ = neg ? (float)HH : fmaf(ry, dep, pr[10]);
    float rpz = neg ? 1.0f : __fdividef(1.0f, pz_);
    float ix = px_ * rpz;      // align_corners=True algebra: ix = px/pz
    float iy = py_ * rpz;
    float x0f = floorf(ix), y0f = floorf(iy);
    float wx1 = ix - x0f, wy1 = iy - y0f;
    float wx0 = 1.0f - wx1, wy0 = 1.0f - wy1;
    float x1f = x0f + 1.0f, y1f = y0f + 1.0f;
    float vx0 = (x0f >= 0.0f && x0f <= (float)(WW - 1)) ? 1.0f : 0.0f;
    float vx1 = (x1f >= 0.0f && x1f <= (float)(WW - 1)) ? 1.0f : 0.0f;
    float vy0 = (y0f >= 0.0f && y0f <= (float)(HH - 1)) ? 1.0f : 0.0f;
    float vy1 = (y1f >= 0.0f && y1f <= (float)(HH - 1)) ? 1.0f : 0.0f;
    int xa = (int)fminf(fmaxf(x0f, 0.0f), (float)(WW - 1));
    int xb = (int)fminf(fmaxf(x1f, 0.0f), (float)(WW - 1));
    int ya = (int)fminf(fmaxf(y0f, 0.0f), (float)(HH - 1));
    int yb = (int)fminf(fmaxf(y1f, 0.0f), (float)(HH - 1));
    float w00 = wx0 * wy0 * vx0 * vy0;   // zeros_pad=True
    float w01 = wx1 * wy0 * vx1 * vy0;
    float w10 = wx0 * wy1 * vx0 * vy1;
    float w11 = wx1 * wy1 * vx0 * vy1 * vx1;   // recomputed below; keep simple
    w11 = wx1 * wy1 * vx1 * vy1;

    int t00 = ya * WW + xa, t01 = ya * WW + xb;
    int t10 = yb * WW + xa, t11 = yb * WW + xb;

    float simf[NGRP];
    {
      const __half* vb = srcT + (size_t)(v * 4) * QPLANE;
      const float TEPS = 1e-3f;
      bool a00 = w00 > TEPS, a01 = w01 > TEPS, a10 = w10 > TEPS, a11 = w11 > TEPS;
      // load-only phase: raw tap data into independent registers
      float4 u0_0, u0_1, u0_2, u0_3;
      float4 u1_0, u1_1, u1_2, u1_3;
      float4 u2_0, u2_1, u2_2, u2_3;
      float4 u3_0, u3_1, u3_2, u3_3;
      if (a00) {
        u0_0 = *(const float4*)(vb + (size_t)0 * QPLANE + (size_t)t00 * 8);
        u0_1 = *(const float4*)(vb + (size_t)1 * QPLANE + (size_t)t00 * 8);
        u0_2 = *(const float4*)(vb + (size_t)2 * QPLANE + (size_t)t00 * 8);
        u0_3 = *(const float4*)(vb + (size_t)3 * QPLANE + (size_t)t00 * 8);
      }
      if (a01) {
        u1_0 = *(const float4*)(vb + (size_t)0 * QPLANE + (size_t)t01 * 8);
        u1_1 = *(const float4*)(vb + (size_t)1 * QPLANE + (size_t)t01 * 8);
        u1_2 = *(const float4*)(vb + (size_t)2 * QPLANE + (size_t)t01 * 8);
        u1_3 = *(const float4*)(vb + (size_t)3 * QPLANE + (size_t)t01 * 8);
      }
      if (a10) {
        u2_0 = *(const float4*)(vb + (size_t)0 * QPLANE + (size_t)t10 * 8);
        u2_1 = *(const float4*)(vb + (size_t)1 * QPLANE + (size_t)t10 * 8);
        u2_2 = *(const float4*)(vb + (size_t)2 * QPLANE + (size_t)t10 * 8);
        u2_3 = *(const float4*)(vb + (size_t)3 * QPLANE + (size_t)t10 * 8);
      }
      if (a11) {
        u3_0 = *(const float4*)(vb + (size_t)0 * QPLANE + (size_t)t11 * 8);
        u3_1 = *(const float4*)(vb + (size_t)1 * QPLANE + (size_t)t11 * 8);
        u3_2 = *(const float4*)(vb + (size_t)2 * QPLANE + (size_t)t11 * 8);
        u3_3 = *(const float4*)(vb + (size_t)3 * QPLANE + (size_t)t11 * 8);
      }
      // blend-only phase (VALU): wp accumulation
      h2 wp[16];
#pragma unroll
      for (int c = 0; c < 16; ++c) wp[c] = h2{(_Float16)0.0f, (_Float16)0.0f};
      if (a00) {
        blend4(u0_0, w00, wp + 0); blend4(u0_1, w00, wp + 4);
        blend4(u0_2, w00, wp + 8); blend4(u0_3, w00, wp + 12);
      }
      if (a01) {
        blend4(u1_0, w01, wp + 0); blend4(u1_1, w01, wp + 4);
        blend4(u1_2, w01, wp + 8); blend4(u1_3, w01, wp + 12);
      }
      if (a10) {
        blend4(u2_0, w10, wp + 0); blend4(u2_1, w10, wp + 4);
        blend4(u2_2, w10, wp + 8); blend4(u2_3, w10, wp + 12);
      }
      if (a11) {
        blend4(u3_0, w11, wp + 0); blend4(u3_1, w11, wp + 4);
        blend4(u3_2, w11, wp + 8); blend4(u3_3, w11, wp + 12);
      }
#pragma unroll
      for (int g = 0; g < NGRP; ++g)
        simf[g] = fdot2_(wp[2*g+1], rc[2*g+1], fdot2_(wp[2*g], rc[2*g], 0.0f));
    }

    float4 xp;
    xp.x = pkf_(simf[0], simf[1]);
    xp.y = pkf_(simf[2], simf[3]);
    xp.z = pkf_(simf[4], simf[5]);
    xp.w = pkf_(simf[6], simf[7]);
    xps[v] = xp;
    scv[v] = mlp_mfma(xp, w0f_pw, w1f_pw, b1s_pw, w2s_pw, b2_pw, lo);
  }

  // ---- phase 2: one barrier, max over d for all 4 views
#pragma unroll
  for (int v = 0; v < NVIEW; ++v) sred[(v << 9) | (d << 6) | lane] = scv[v];
  __syncthreads();

  // ---- phase 3: view weights + accumulation
  float ssum[NGRP];
#pragma unroll
  for (int g = 0; g < NGRP; ++g) ssum[g] = 0.0f;
  float wsum = 0.0f;
#pragma unroll
  for (int v = 0; v < NVIEW; ++v) {
    float m = sred[(v << 9) | lane];
#pragma unroll
    for (int j = 1; j < NDEP; ++j) m = fmaxf(m, sred[(v << 9) | (j << 6) | lane]);
    float vw = __fdividef(1.0f, 1.0f + __expf(-m));
    // unpack this view's f16 sims (error << tolerance; sims already f16-dot products)
    h2 p0 = __builtin_bit_cast(h2, xps[v].x);
    h2 p1 = __builtin_bit_cast(h2, xps[v].y);
    h2 p2 = __builtin_bit_cast(h2, xps[v].z);
    h2 p3 = __builtin_bit_cast(h2, xps[v].w);
    ssum[0] = fmaf((float)p0.x, vw, ssum[0]);
    ssum[1] = fmaf((float)p0.y, vw, ssum[1]);
    ssum[2] = fmaf((float)p1.x, vw, ssum[2]);
    ssum[3] = fmaf((float)p1.y, vw, ssum[3]);
    ssum[4] = fmaf((float)p2.x, vw, ssum[4]);
    ssum[5] = fmaf((float)p2.y, vw, ssum[5]);
    ssum[6] = fmaf((float)p3.x, vw, ssum[6]);
    ssum[7] = fmaf((float)p3.y, vw, ssum[7]);
    wsum += vw;
    if (d == 0) outVW[v * HWPIX + pix] = vw;   // coalesced
  }

  float rw = __fdividef(1.0f, wsum);
  float4 xg;
  xg.x = pkf_(ssum[0] * rw, ssum[1] * rw);
  xg.y = pkf_(ssum[2] * rw, ssum[3] * rw);
  xg.z = pkf_(ssum[4] * rw, ssum[5] * rw);
  xg.w = pkf_(ssum[6] * rw, ssum[7] * rw);
  // sn-net fragments (loaded late to limit live range)
  h8v w0f_sn = ((const h8v*)(wsc + OFF_TAB + 1024))[lane];
  h8v w1f_sn = ((const h8v*)(wsc + OFF_TAB + 1024 + 256))[lane];
  float4 b1s_sn = ((const float4*)(wsc + OFF_TAB + 1024 + 512))[lane];
  float4 w2s_sn = ((const float4*)(wsc + OFF_TAB + 1024 + 768))[lane];
  float b2_sn = wsc[63];
  float yv = mlp_mfma(xg, w0f_sn, w1f_sn, b1s_sn, w2s_sn, b2_sn, lo);
  ybuf[pix * NDEP + d] = yv;             // [pix][d] for k_score
}

// -------- score: thread-per-pixel, in-register softmax over d
__global__ __launch_bounds__(256) void k_score(
    const float* __restrict__ grid, const float* __restrict__ weight,
    const float* __restrict__ depthS, const float* __restrict__ ybuf,
    float* __restrict__ out) {
  int pix = blockIdx.x * 256 + threadIdx.x;
  int h = pix / WW;
  int w = pix - h * WW;
  float sv[NDEP];
#pragma unroll
  for (int d = 0; d < NDEP; ++d) sv[d] = 0.0f;

#pragma unroll 1
  for (int n = 0; n < NNEI; ++n) {
    int gi = ((n * HH + h) * WW + w) * 2;
    float gx = grid[gi], gy = grid[gi + 1];
    float ix = ((gx + 1.0f) * (float)WW - 1.0f) * 0.5f;  // align_corners=False
    float iy = ((gy + 1.0f) * (float)HH - 1.0f) * 0.5f;
    float x0f = floorf(ix), y0f = floorf(iy);
    float wx1 = ix - x0f, wy1 = iy - y0f;
    float wx0 = 1.0f - wx1, wy0 = 1.0f - wy1;
    int xa = (int)fminf(fmaxf(x0f, 0.0f), (float)(WW - 1));
    int xb = (int)fminf(fmaxf(x0f + 1.0f, 0.0f), (float)(WW - 1));
    int ya = (int)fminf(fmaxf(y0f, 0.0f), (float)(HH - 1));
    int yb2 = (int)fminf(fmaxf(y0f + 1.0f, 0.0f), (float)(HH - 1));
    const float4* p00 = reinterpret_cast<const float4*>(ybuf + (size_t)(ya * WW + xa) * NDEP);
    const float4* p01 = reinterpret_cast<const float4*>(ybuf + (size_t)(ya * WW + xb) * NDEP);
    const float4* p10 = reinterpret_cast<const float4*>(ybuf + (size_t)(yb2 * WW + xa) * NDEP);
    const float4* p11 = reinterpret_cast<const float4*>(ybuf + (size_t)(yb2 * WW + xb) * NDEP);
    float4 a00 = p00[0], b00 = p00[1];
    float4 a01 = p01[0], b01 = p01[1];
    float4 a10 = p10[0], b10 = p10[1];
    float4 a11 = p11[0], b11 = p11[1];
    const float* v00 = (const float*)&a00;
    const float* v01 = (const float*)&a01;
    const float* v10 = (const float*)&a10;
    const float* v11 = (const float*)&a11;
    const float* u00 = (const float*)&b00;
    const float* u01 = (const float*)&b01;
    const float* u10 = (const float*)&b10;
    const float* u11 = (const float*)&b11;
#pragma unroll
    for (int d = 0; d < NDEP; ++d) {
      float c00 = (d < 4) ? v00[d] : u00[d - 4];
      float c01 = (d < 4) ? v01[d] : u01[d - 4];
      float c10 = (d < 4) ? v10[d] : u10[d - 4];
      float c11 = (d < 4) ? v11[d] : u11[d - 4];
      float s = wy0 * fmaf(wx0, c00, wx1 * c01) + wy1 * fmaf(wx0, c10, wx1 * c11);
      float wn = weight[((size_t)(d * NNEI + n) * HH + h) * WW + w];
      sv[d] = fmaf(s, wn, sv[d]);
    }
  }
  float m = sv[0];
#pragma unroll
  for (int d = 1; d < NDEP; ++d) m = fmaxf(m, sv[d]);
  float e[NDEP], s8 = 0.0f;
#pragma unroll
  for (int d = 0; d < NDEP; ++d) { e[d] = __expf(sv[d] - m); s8 += e[d]; }
  float r = __fdividef(1.0f, s8);
  float dp = 0.0f;
#pragma unroll
  for (int d = 0; d < NDEP; ++d) {
    float sc = e[d] * r;
    out[HWPIX + d * HWPIX + pix] = sc;     // score
    dp = fmaf(depthS[d * HWPIX + pix], sc, dp);   // coalesced per d
  }
  out[pix] = dp;                           // depth
}

extern "C" void kernel_launch(void* const* d_in, const int* in_sizes, int n_in,
                              void* d_out, int out_size, void* d_ws, size_t ws_size,
                              hipStream_t stream) {
  const float* ref    = (const float*)d_in[0];
  const float* src    = (const float*)d_in[1];
  const float* refP   = (const float*)d_in[2];
  const float* srcP   = (const float*)d_in[3];
  const float* depthS = (const float*)d_in[4];
  const float* grid   = (const float*)d_in[5];
  const float* weight = (const float*)d_in[6];
  float* out = (float*)d_out;
  float* ws  = (float*)d_ws;
  __half* srcT = (__half*)(ws + OFF_SRCT);

  int transThreads = 20 * HWPIX;
  int nTransBlocks = transThreads / 256;            // exact: 1536000/256 = 6000

  k_prep<<<nTransBlocks + 1, 256, 0, stream>>>(
      src, ref, srcT, refP, srcP,
      (const float*)d_in[7],  (const float*)d_in[8],
      (const float*)d_in[9],  (const float*)d_in[10],
      (const float*)d_in[11], (const float*)d_in[12],
      (const float*)d_in[13], (const float*)d_in[14],
      (const float*)d_in[15], (const float*)d_in[16],
      (const float*)d_in[17], (const float*)d_in[18],
      ws, nTransBlocks);
  k_main<<<HWPIX / 64, 512, 0, stream>>>(srcT, depthS, ws, ws + OFF_Y, out + 9 * HWPIX);
  k_score<<<HWPIX / 256, 256, 0, stream>>>(grid, weight, depthS, ws + OFF_Y, out);
}

// Round 16
// 76.828 us; speedup vs baseline: 1.0663x; 1.0663x over previous
//
#include <hip/hip_runtime.h>
#include <hip/hip_fp16.h>
#include <cstdint>
#include <cstddef>

#define HH 240
#define WW 320
#define HWPIX 76800
#define NVIEW 4
#define NCH 32
#define NGRP 8
#define NDEP 8
#define NNEI 9
#define QPLANE (HWPIX * 8)     // halfs per quarter-plane (8 ch/pixel)

// ws layout (floats):
// [0..48)   proj: 4 views * 12 (rot 9 row-major, trans 3)
// [62],[63] b2 for pw / sn
// [64..)    per-lane MFMA fragment tables, per net (stride 1024 floats)
#define OFF_TAB 64
#define OFF_Y    4096                     // NDEP*HWPIX f32, layout [pix][d]
#define OFF_SRCT 618496                   // as __half*: 20 quarter-planes (16 src + 4 ref)

typedef _Float16 h2 __attribute__((ext_vector_type(2)));
typedef __fp16  h8v __attribute__((ext_vector_type(8)));
typedef float f32x16 __attribute__((ext_vector_type(16)));

__device__ __forceinline__ float fdot2_(h2 a, h2 b, float c) {
#if __has_builtin(__builtin_amdgcn_fdot2)
  return __builtin_amdgcn_fdot2(a, b, c, false);
#else
  return c + (float)a.x * (float)b.x + (float)a.y * (float)b.y;
#endif
}
__device__ __forceinline__ h2 pk_(float a, float b) {
#if __has_builtin(__builtin_amdgcn_cvt_pkrtz)
  return __builtin_bit_cast(h2, __builtin_amdgcn_cvt_pkrtz(a, b));
#else
  h2 r; r.x = (_Float16)a; r.y = (_Float16)b; return r;
#endif
}
__device__ __forceinline__ float pkf_(float a, float b) {
  return __builtin_bit_cast(float, pk_(a, b));
}

__device__ __forceinline__ f32x16 mfma_(h8v a, h8v b, f32x16 c) {
  return __builtin_amdgcn_mfma_f32_32x32x16_f16(a, b, c, 0, 0, 0);
}

// Wave-batched MLP 8->16->8->1 via 32x32x16 f16 MFMA (layer0 bias in K-slots 8..15)
__device__ __forceinline__ float mlp_mfma(float4 x4, h8v w0f, h8v w1f,
                                          float4 b1s, float4 w2s, float b2v,
                                          bool lo) {
  f32x16 Z = {};
  float4 xsw;
  xsw.x = __shfl_xor(x4.x, 32, 64);
  xsw.y = __shfl_xor(x4.y, 32, 64);
  xsw.z = __shfl_xor(x4.z, 32, 64);
  xsw.w = __shfl_xor(x4.w, 32, 64);
  float4 cst;
  cst.x = __builtin_bit_cast(float, 0x00003C00u);   // h2(1.0, 0) -> bias K-slot
  cst.y = 0.0f; cst.z = 0.0f; cst.w = 0.0f;
  float4 blo, bhi;
  blo.x = lo ? x4.x : cst.x;  blo.y = lo ? x4.y : cst.y;
  blo.z = lo ? x4.z : cst.z;  blo.w = lo ? x4.w : cst.w;
  bhi.x = lo ? xsw.x : cst.x; bhi.y = lo ? xsw.y : cst.y;
  bhi.z = lo ? xsw.z : cst.z; bhi.w = lo ? xsw.w : cst.w;

  float yv0 = 0.0f, yv1 = 0.0f;
#pragma unroll
  for (int bb = 0; bb < 2; ++bb) {
    float4 bin = bb ? bhi : blo;
    f32x16 acc = mfma_(w0f, __builtin_bit_cast(h8v, bin), Z);
    float dw0 = pkf_(fmaxf(acc[0], 0.f), fmaxf(acc[1], 0.f));
    float dw1 = pkf_(fmaxf(acc[2], 0.f), fmaxf(acc[3], 0.f));
    float dw2 = pkf_(fmaxf(acc[4], 0.f), fmaxf(acc[5], 0.f));
    float dw3 = pkf_(fmaxf(acc[6], 0.f), fmaxf(acc[7], 0.f));
    float s0 = __shfl_xor(dw0, 32, 64);
    float s1 = __shfl_xor(dw1, 32, 64);
    float s2 = __shfl_xor(dw2, 32, 64);
    float s3 = __shfl_xor(dw3, 32, 64);
    float4 bf;
    bf.x = lo ? dw0 : s2;
    bf.y = lo ? dw1 : s3;
    bf.z = lo ? s0 : dw2;
    bf.w = lo ? s1 : dw3;
    f32x16 a2 = mfma_(w1f, __builtin_bit_cast(h8v, bf), Z);
    float p = fmaxf(a2[0] + b1s.x, 0.f) * w2s.x;
    p = fmaf(fmaxf(a2[1] + b1s.y, 0.f), w2s.y, p);
    p = fmaf(fmaxf(a2[2] + b1s.z, 0.f), w2s.z, p);
    p = fmaf(fmaxf(a2[3] + b1s.w, 0.f), w2s.w, p);
    p += __shfl_xor(p, 32, 64);
    if (bb) yv1 = p + b2v; else yv0 = p + b2v;
  }
  return lo ? yv0 : yv1;
}

// -------- prep: transpose+convert features into quarter-planes; last block = setup
__global__ __launch_bounds__(256) void k_prep(
    const float* __restrict__ src, const float* __restrict__ ref,
    __half* __restrict__ dst,
    const float* __restrict__ refP, const float* __restrict__ srcP,
    const float* __restrict__ pw0, const float* __restrict__ pbn0,
    const float* __restrict__ pw1, const float* __restrict__ pbn1,
    const float* __restrict__ pw2, const float* __restrict__ pb2,
    const float* __restrict__ sw0, const float* __restrict__ sbn0,
    const float* __restrict__ sw1, const float* __restrict__ sbn1,
    const float* __restrict__ sw2, const float* __restrict__ sb2,
    float* __restrict__ ws, int nTransBlocks) {
  if ((int)blockIdx.x == nTransBlocks) {
    int tid = threadIdx.x;
    if (tid < 128) {
      int net = tid >> 6;
      int l = tid & 63;
      int n = l & 31;
      int hi = l >> 5;
      const float* W0 = net ? sw0 : pw0;  const float* B0 = net ? sbn0 : pbn0;
      const float* W1 = net ? sw1 : pw1;  const float* B1 = net ? sbn1 : pbn1;
      const float* W2 = net ? sw2 : pw2;
      float* base = ws + OFF_TAB + net * 1024;
      float4 r;
      if (hi == 0 && n < 16) {
        float s = B0[n] / sqrtf(B0[48 + n] + 1e-5f) * 0.25f;
        r.x = pkf_(W0[n * 8 + 0] * s, W0[n * 8 + 1] * s);
        r.y = pkf_(W0[n * 8 + 2] * s, W0[n * 8 + 3] * s);
        r.z = pkf_(W0[n * 8 + 4] * s, W0[n * 8 + 5] * s);
        r.w = pkf_(W0[n * 8 + 6] * s, W0[n * 8 + 7] * s);
      } else if (hi == 1 && n < 16) {
        float s = B0[n] / sqrtf(B0[48 + n] + 1e-5f);
        float b0f = B0[16 + n] - B0[32 + n] * s;
        r.x = pkf_(b0f, 0.f); r.y = 0.f; r.z = 0.f; r.w = 0.f;
      } else { r.x = r.y = r.z = r.w = 0.f; }
      ((float4*)(base))[l] = r;
      float4 q;
      if (n < 8) {
        float s = B1[n] / sqrtf(B1[24 + n] + 1e-5f);
        int o = n * 16 + 8 * hi;
        q.x = pkf_(W1[o + 0] * s, W1[o + 1] * s);
        q.y = pkf_(W1[o + 2] * s, W1[o + 3] * s);
        q.z = pkf_(W1[o + 4] * s, W1[o + 5] * s);
        q.w = pkf_(W1[o + 6] * s, W1[o + 7] * s);
      } else { q.x = q.y = q.z = q.w = 0.f; }
      ((float4*)(base + 256))[l] = q;
      float4 b;
      {
        float bb[4];
        for (int rr = 0; rr < 4; ++rr) {
          int o = rr + 4 * hi;
          float s = B1[o] / sqrtf(B1[24 + o] + 1e-5f);
          bb[rr] = B1[8 + o] - B1[16 + o] * s;
        }
        b.x = bb[0]; b.y = bb[1]; b.z = bb[2]; b.w = bb[3];
      }
      ((float4*)(base + 512))[l] = b;
      float4 w2v;
      w2v.x = W2[0 + 4 * hi]; w2v.y = W2[1 + 4 * hi];
      w2v.z = W2[2 + 4 * hi]; w2v.w = W2[3 + 4 * hi];
      ((float4*)(base + 768))[l] = w2v;
    } else if (tid == 128) {
      ws[62] = pb2[0];
      ws[63] = sb2[0];
    } else if (tid == 129) {
      float a[4][8];
      for (int i = 0; i < 4; ++i)
        for (int j = 0; j < 4; ++j) { a[i][j] = refP[i * 4 + j]; a[i][4 + j] = (i == j) ? 1.0f : 0.0f; }
      for (int c = 0; c < 4; ++c) {
        int piv = c; float best = fabsf(a[c][c]);
        for (int r2 = c + 1; r2 < 4; ++r2) { float t = fabsf(a[r2][c]); if (t > best) { best = t; piv = r2; } }
        if (piv != c) for (int j = 0; j < 8; ++j) { float t = a[c][j]; a[c][j] = a[piv][j]; a[piv][j] = t; }
        float inv = 1.0f / a[c][c];
        for (int j = 0; j < 8; ++j) a[c][j] *= inv;
        for (int r2 = 0; r2 < 4; ++r2) if (r2 != c) {
          float f = a[r2][c];
          for (int j = 0; j < 8; ++j) a[r2][j] -= f * a[c][j];
        }
      }
      for (int v = 0; v < NVIEW; ++v) {
        const float* S = srcP + v * 16;
        for (int i = 0; i < 3; ++i)
          for (int j = 0; j < 4; ++j) {
            float p = S[i*4+0]*a[0][4+j] + S[i*4+1]*a[1][4+j] + S[i*4+2]*a[2][4+j] + S[i*4+3]*a[3][4+j];
            if (j < 3) ws[v * 12 + i * 3 + j] = p;
            else       ws[v * 12 + 9 + i] = p;
          }
      }
    }
    return;
  }
  int t = blockIdx.x * 256 + threadIdx.x;
  int vq = t / HWPIX;                    // quarter-plane index 0..19 ((v*4+q); v==4 -> ref)
  int pix = t - vq * HWPIX;
  int v = vq >> 2;
  int q = vq & 3;
  const float* s = (v < NVIEW) ? (src + ((size_t)(v * NCH + q * 8)) * HWPIX + pix)
                               : (ref + ((size_t)(q * 8)) * HWPIX + pix);
  union { h2 h[4]; float4 f; } u;
  u.h[0] = pk_(s[0],         s[HWPIX]);
  u.h[1] = pk_(s[2 * HWPIX], s[3 * HWPIX]);
  u.h[2] = pk_(s[4 * HWPIX], s[5 * HWPIX]);
  u.h[3] = pk_(s[6 * HWPIX], s[7 * HWPIX]);
  reinterpret_cast<float4*>(dst + (size_t)vq * QPLANE)[pix] = u.f;
}

// one 16B tap load (8 channels of quarter q), accumulated into wp[0..3] with weight wtf
__device__ __forceinline__ void tapq(const __half* __restrict__ p, float wtf,
                                     h2* __restrict__ wp) {
  _Float16 wh = (_Float16)wtf;
  h2 wt2 = h2{wh, wh};
  union { float4 f; h2 h[4]; } u;
  u.f = *reinterpret_cast<const float4*>(p);
#pragma unroll
  for (int c = 0; c < 4; ++c) wp[c] += u.h[c] * wt2;
}

// -------- main fused kernel. Block = 512 threads = 8 waves: wave d handles
// 64 CONSECUTIVE pixels at depth index d (coalesced taps). Phase 1 computes
// all 4 views' sims + pw-scores with NO barriers; one barrier + LDS reduce
// does max-over-d for all views; phase 3 accumulates.
// Zero-weight tap skipping: axis-aligned view translations make half the
// bilinear weights ~0 (wy1~1e-4 for horizontal views, wx1~1e-4 for vertical);
// guarding each tap with (wt > 1e-3) halves both tap loads and blend VALU,
// with error <= 1e-3 * |feature| (orders below the tolerance margin).
__global__ __launch_bounds__(512, 2) void k_main(
    const __half* __restrict__ srcT, const float* __restrict__ depthS,
    const float* __restrict__ wsc,
    float* __restrict__ ybuf, float* __restrict__ outVW) {
  __shared__ float sred[NVIEW * NDEP * 64];
  int tid = threadIdx.x;
  int lane = tid & 63;
  int d = tid >> 6;                      // wave id = depth index
  bool lo = lane < 32;
  // XCD-aware swizzle: 1200 blocks = 8 XCDs x 150 contiguous; bijective.
  int bid = (int)blockIdx.x;
  int swz = (bid & 7) * 150 + (bid >> 3);
  int pix = swz * 64 + lane;             // 64 consecutive pixels per wave
  int h = pix / WW;                      // uniform per wave (64 | 320)
  int w = pix - h * WW;
  float fx = (float)w, fy = (float)h;

  // pw-net fragments
  h8v w0f_pw = ((const h8v*)(wsc + OFF_TAB))[lane];
  h8v w1f_pw = ((const h8v*)(wsc + OFF_TAB + 256))[lane];
  float4 b1s_pw = ((const float4*)(wsc + OFF_TAB + 512))[lane];
  float4 w2s_pw = ((const float4*)(wsc + OFF_TAB + 768))[lane];
  float b2_pw = wsc[62];

  // ref channels: 4 quarter-plane loads, fully coalesced
  h2 rc[16];
  {
    const __half* refb = srcT + (size_t)16 * QPLANE;
#pragma unroll
    for (int q = 0; q < 4; ++q) {
      union { float4 f; h2 hh[4]; } u;
      u.f = *reinterpret_cast<const float4*>(refb + (size_t)q * QPLANE + (size_t)pix * 8);
      rc[4*q] = u.hh[0]; rc[4*q+1] = u.hh[1]; rc[4*q+2] = u.hh[2]; rc[4*q+3] = u.hh[3];
    }
  }
  float dep = depthS[d * HWPIX + pix];   // coalesced (same d across wave)

  // ---- phase 1: all views, no barriers (fully unrolled: arrays stay in regs)
  float4 xps[NVIEW];
  float scv[NVIEW];
#pragma unroll
  for (int v = 0; v < NVIEW; ++v) {
    const float* pr = wsc + v * 12;
    float rx = fmaf(pr[0], fx, fmaf(pr[1], fy, pr[2]));
    float ry = fmaf(pr[3], fx, fmaf(pr[4], fy, pr[5]));
    float rz = fmaf(pr[6], fx, fmaf(pr[7], fy, pr[8]));
    float pz_ = fmaf(rz, dep, pr[11]);
    bool neg = (pz_ <= 0.001f);
    float px_ = neg ? (float)WW : fmaf(rx, dep, pr[9]);
    float py_ = neg ? (float)HH : fmaf(ry, dep, pr[10]);
    float rpz = neg ? 1.0f : __fdividef(1.0f, pz_);
    float ix = px_ * rpz;      // align_corners=True algebra: ix = px/pz
    float iy = py_ * rpz;
    float x0f = floorf(ix), y0f = floorf(iy);
    float wx1 = ix - x0f, wy1 = iy - y0f;
    float wx0 = 1.0f - wx1, wy0 = 1.0f - wy1;
    float x1f = x0f + 1.0f, y1f = y0f + 1.0f;
    float vx0 = (x0f >= 0.0f && x0f <= (float)(WW - 1)) ? 1.0f : 0.0f;
    float vx1 = (x1f >= 0.0f && x1f <= (float)(WW - 1)) ? 1.0f : 0.0f;
    float vy0 = (y0f >= 0.0f && y0f <= (float)(HH - 1)) ? 1.0f : 0.0f;
    float vy1 = (y1f >= 0.0f && y1f <= (float)(HH - 1)) ? 1.0f : 0.0f;
    int xa = (int)fminf(fmaxf(x0f, 0.0f), (float)(WW - 1));
    int xb = (int)fminf(fmaxf(x1f, 0.0f), (float)(WW - 1));
    int ya = (int)fminf(fmaxf(y0f, 0.0f), (float)(HH - 1));
    int yb = (int)fminf(fmaxf(y1f, 0.0f), (float)(HH - 1));
    float w00 = wx0 * wy0 * vx0 * vy0;   // zeros_pad=True
    float w01 = wx1 * wy0 * vx1 * vy0;
    float w10 = wx0 * wy1 * vx0 * vy1;
    float w11 = wx1 * wy1 * vx1 * vy1;

    int t00 = ya * WW + xa, t01 = ya * WW + xb;
    int t10 = yb * WW + xa, t11 = yb * WW + xb;

    float simf[NGRP];
    {
      const __half* vb = srcT + (size_t)(v * 4) * QPLANE;
      h2 wp[16];
#pragma unroll
      for (int c = 0; c < 16; ++c) wp[c] = h2{(_Float16)0.0f, (_Float16)0.0f};
      const float TEPS = 1e-3f;
      if (w00 > TEPS) {
#pragma unroll
        for (int q = 0; q < 4; ++q)
          tapq(vb + (size_t)q * QPLANE + (size_t)t00 * 8, w00, wp + 4 * q);
      }
      if (w01 > TEPS) {
#pragma unroll
        for (int q = 0; q < 4; ++q)
          tapq(vb + (size_t)q * QPLANE + (size_t)t01 * 8, w01, wp + 4 * q);
      }
      if (w10 > TEPS) {
#pragma unroll
        for (int q = 0; q < 4; ++q)
          tapq(vb + (size_t)q * QPLANE + (size_t)t10 * 8, w10, wp + 4 * q);
      }
      if (w11 > TEPS) {
#pragma unroll
        for (int q = 0; q < 4; ++q)
          tapq(vb + (size_t)q * QPLANE + (size_t)t11 * 8, w11, wp + 4 * q);
      }
#pragma unroll
      for (int g = 0; g < NGRP; ++g)
        simf[g] = fdot2_(wp[2*g+1], rc[2*g+1], fdot2_(wp[2*g], rc[2*g], 0.0f));
    }

    float4 xp;
    xp.x = pkf_(simf[0], simf[1]);
    xp.y = pkf_(simf[2], simf[3]);
    xp.z = pkf_(simf[4], simf[5]);
    xp.w = pkf_(simf[6], simf[7]);
    xps[v] = xp;
    scv[v] = mlp_mfma(xp, w0f_pw, w1f_pw, b1s_pw, w2s_pw, b2_pw, lo);
  }

  // ---- phase 2: one barrier, max over d for all 4 views
#pragma unroll
  for (int v = 0; v < NVIEW; ++v) sred[(v << 9) | (d << 6) | lane] = scv[v];
  __syncthreads();

  // ---- phase 3: view weights + accumulation
  float ssum[NGRP];
#pragma unroll
  for (int g = 0; g < NGRP; ++g) ssum[g] = 0.0f;
  float wsum = 0.0f;
#pragma unroll
  for (int v = 0; v < NVIEW; ++v) {
    float m = sred[(v << 9) | lane];
#pragma unroll
    for (int j = 1; j < NDEP; ++j) m = fmaxf(m, sred[(v << 9) | (j << 6) | lane]);
    float vw = __fdividef(1.0f, 1.0f + __expf(-m));
    // unpack this view's f16 sims (error << tolerance; sims already f16-dot products)
    h2 p0 = __builtin_bit_cast(h2, xps[v].x);
    h2 p1 = __builtin_bit_cast(h2, xps[v].y);
    h2 p2 = __builtin_bit_cast(h2, xps[v].z);
    h2 p3 = __builtin_bit_cast(h2, xps[v].w);
    ssum[0] = fmaf((float)p0.x, vw, ssum[0]);
    ssum[1] = fmaf((float)p0.y, vw, ssum[1]);
    ssum[2] = fmaf((float)p1.x, vw, ssum[2]);
    ssum[3] = fmaf((float)p1.y, vw, ssum[3]);
    ssum[4] = fmaf((float)p2.x, vw, ssum[4]);
    ssum[5] = fmaf((float)p2.y, vw, ssum[5]);
    ssum[6] = fmaf((float)p3.x, vw, ssum[6]);
    ssum[7] = fmaf((float)p3.y, vw, ssum[7]);
    wsum += vw;
    if (d == 0) outVW[v * HWPIX + pix] = vw;   // coalesced
  }

  float rw = __fdividef(1.0f, wsum);
  float4 xg;
  xg.x = pkf_(ssum[0] * rw, ssum[1] * rw);
  xg.y = pkf_(ssum[2] * rw, ssum[3] * rw);
  xg.z = pkf_(ssum[4] * rw, ssum[5] * rw);
  xg.w = pkf_(ssum[6] * rw, ssum[7] * rw);
  // sn-net fragments (loaded late to limit live range)
  h8v w0f_sn = ((const h8v*)(wsc + OFF_TAB + 1024))[lane];
  h8v w1f_sn = ((const h8v*)(wsc + OFF_TAB + 1024 + 256))[lane];
  float4 b1s_sn = ((const float4*)(wsc + OFF_TAB + 1024 + 512))[lane];
  float4 w2s_sn = ((const float4*)(wsc + OFF_TAB + 1024 + 768))[lane];
  float b2_sn = wsc[63];
  float yv = mlp_mfma(xg, w0f_sn, w1f_sn, b1s_sn, w2s_sn, b2_sn, lo);
  ybuf[pix * NDEP + d] = yv;             // [pix][d] for k_score
}

// -------- score: thread-per-pixel, in-register softmax over d
__global__ __launch_bounds__(256) void k_score(
    const float* __restrict__ grid, const float* __restrict__ weight,
    const float* __restrict__ depthS, const float* __restrict__ ybuf,
    float* __restrict__ out) {
  int pix = blockIdx.x * 256 + threadIdx.x;
  int h = pix / WW;
  int w = pix - h * WW;
  float sv[NDEP];
#pragma unroll
  for (int d = 0; d < NDEP; ++d) sv[d] = 0.0f;

#pragma unroll 1
  for (int n = 0; n < NNEI; ++n) {
    int gi = ((n * HH + h) * WW + w) * 2;
    float gx = grid[gi], gy = grid[gi + 1];
    float ix = ((gx + 1.0f) * (float)WW - 1.0f) * 0.5f;  // align_corners=False
    float iy = ((gy + 1.0f) * (float)HH - 1.0f) * 0.5f;
    float x0f = floorf(ix), y0f = floorf(iy);
    float wx1 = ix - x0f, wy1 = iy - y0f;
    float wx0 = 1.0f - wx1, wy0 = 1.0f - wy1;
    int xa = (int)fminf(fmaxf(x0f, 0.0f), (float)(WW - 1));
    int xb = (int)fminf(fmaxf(x0f + 1.0f, 0.0f), (float)(WW - 1));
    int ya = (int)fminf(fmaxf(y0f, 0.0f), (float)(HH - 1));
    int yb2 = (int)fminf(fmaxf(y0f + 1.0f, 0.0f), (float)(HH - 1));
    const float4* p00 = reinterpret_cast<const float4*>(ybuf + (size_t)(ya * WW + xa) * NDEP);
    const float4* p01 = reinterpret_cast<const float4*>(ybuf + (size_t)(ya * WW + xb) * NDEP);
    const float4* p10 = reinterpret_cast<const float4*>(ybuf + (size_t)(yb2 * WW + xa) * NDEP);
    const float4* p11 = reinterpret_cast<const float4*>(ybuf + (size_t)(yb2 * WW + xb) * NDEP);
    float4 a00 = p00[0], b00 = p00[1];
    float4 a01 = p01[0], b01 = p01[1];
    float4 a10 = p10[0], b10 = p10[1];
    float4 a11 = p11[0], b11 = p11[1];
    const float* v00 = (const float*)&a00;
    const float* v01 = (const float*)&a01;
    const float* v10 = (const float*)&a10;
    const float* v11 = (const float*)&a11;
    const float* u00 = (const float*)&b00;
    const float* u01 = (const float*)&b01;
    const float* u10 = (const float*)&b10;
    const float* u11 = (const float*)&b11;
#pragma unroll
    for (int d = 0; d < NDEP; ++d) {
      float c00 = (d < 4) ? v00[d] : u00[d - 4];
      float c01 = (d < 4) ? v01[d] : u01[d - 4];
      float c10 = (d < 4) ? v10[d] : u10[d - 4];
      float c11 = (d < 4) ? v11[d] : u11[d - 4];
      float s = wy0 * fmaf(wx0, c00, wx1 * c01) + wy1 * fmaf(wx0, c10, wx1 * c11);
      float wn = weight[((size_t)(d * NNEI + n) * HH + h) * WW + w];
      sv[d] = fmaf(s, wn, sv[d]);
    }
  }
  float m = sv[0];
#pragma unroll
  for (int d = 1; d < NDEP; ++d) m = fmaxf(m, sv[d]);
  float e[NDEP], s8 = 0.0f;
#pragma unroll
  for (int d = 0; d < NDEP; ++d) { e[d] = __expf(sv[d] - m); s8 += e[d]; }
  float r = __fdividef(1.0f, s8);
  float dp = 0.0f;
#pragma unroll
  for (int d = 0; d < NDEP; ++d) {
    float sc = e[d] * r;
    out[HWPIX + d * HWPIX + pix] = sc;     // score
    dp = fmaf(depthS[d * HWPIX + pix], sc, dp);   // coalesced per d
  }
  out[pix] = dp;                           // depth
}

extern "C" void kernel_launch(void* const* d_in, const int* in_sizes, int n_in,
                              void* d_out, int out_size, void* d_ws, size_t ws_size,
                              hipStream_t stream) {
  const float* ref    = (const float*)d_in[0];
  const float* src    = (const float*)d_in[1];
  const float* refP   = (const float*)d_in[2];
  const float* srcP   = (const float*)d_in[3];
  const float* depthS = (const float*)d_in[4];
  const float* grid   = (const float*)d_in[5];
  const float* weight = (const float*)d_in[6];
  float* out = (float*)d_out;
  float* ws  = (float*)d_ws;
  __half* srcT = (__half*)(ws + OFF_SRCT);

  int transThreads = 20 * HWPIX;
  int nTransBlocks = transThreads / 256;            // exact: 1536000/256 = 6000

  k_prep<<<nTransBlocks + 1, 256, 0, stream>>>(
      src, ref, srcT, refP, srcP,
      (const float*)d_in[7],  (const float*)d_in[8],
      (const float*)d_in[9],  (const float*)d_in[10],
      (const float*)d_in[11], (const float*)d_in[12],
      (const float*)d_in[13], (const float*)d_in[14],
      (const float*)d_in[15], (const float*)d_in[16],
      (const float*)d_in[17], (const float*)d_in[18],
      ws, nTransBlocks);
  k_main<<<HWPIX / 64, 512, 0, stream>>>(srcT, depthS, ws, ws + OFF_Y, out + 9 * HWPIX);
  k_score<<<HWPIX / 256, 256, 0, stream>>>(grid, weight, depthS, ws + OFF_Y, out);
}